// Round 2
// baseline (370.064 us; speedup 1.0000x reference)
//
#include <hip/hip_runtime.h>
#include <hip/hip_bf16.h>

// CustomModel_60851096649964: two-stage biased top-k attention, folded weights.
// R2: back half (u@VP1 -> yS2 -> self-attn -> @VP2) fused into one per-4-batch
// kernel (Z-trick: out = sum_h sum_k w2 * (y[k]@VP2_h)); attn_cross XCD-swizzled.

typedef __attribute__((ext_vector_type(4))) float f32x4;
typedef __attribute__((ext_vector_type(8))) short bf16x8v;
typedef __attribute__((ext_vector_type(4))) short short4v;

#define BT_N 2880
#define A_N  10
#define M_N  350
#define BQ_N (BT_N * A_N)   // 28800
#define DIMC 128

static __device__ __forceinline__ short f2b(float x) {
    __hip_bfloat16 b = __float2bfloat16(x);
    return __builtin_bit_cast(short, b);
}
static __device__ __forceinline__ float b2f(short s) {
    unsigned u = ((unsigned)(unsigned short)s) << 16;
    return __builtin_bit_cast(float, u);
}

// ---------------------------------------------------------------------------
// K0: folded per-head matrices (bf16, transposed for B^T GEMM). Unchanged.
// ---------------------------------------------------------------------------
__global__ __launch_bounds__(256) void precompute_mats(
    const float* __restrict__ Wq, const float* __restrict__ Wk,
    const float* __restrict__ Wv, const float* __restrict__ Wcp,
    const float* __restrict__ Wc, const float* __restrict__ Wsp,
    short* __restrict__ S1t, short* __restrict__ VP1t,
    short* __restrict__ S2t, short* __restrict__ VP2t)
{
    int gid = blockIdx.x * 256 + threadIdx.x;
    int mat = gid >> 17;
    int idx = gid & 131071;
    float acc = 0.f;
    if (mat == 0) {
        int n = idx >> 7, c = idx & 127;
        int h = n >> 7, d = n & 127;
        #pragma unroll
        for (int t = 0; t < 16; ++t)
            acc += Wq[c * 128 + h * 16 + t] * Wk[d * 128 + h * 16 + t];
        S1t[idx] = f2b(acc * 0.25f);
    } else if (mat == 1) {
        int d = idx >> 10, o = idx & 1023;
        int h = o >> 7, c = o & 127;
        #pragma unroll
        for (int t = 0; t < 16; ++t)
            acc += Wv[c * 128 + h * 16 + t] * Wcp[(h * 16 + t) * 128 + d];
        VP1t[idx] = f2b(acc);
    } else if (mat == 2) {
        int n = idx >> 7, c = idx & 127;
        int h = n >> 7, d = n & 127;
        #pragma unroll
        for (int t = 0; t < 16; ++t)
            acc += Wc[c * 384 + h * 16 + t] * Wc[d * 384 + 128 + h * 16 + t];
        S2t[idx] = f2b(acc * 0.25f);
    } else {
        int d = idx >> 10, o = idx & 1023;
        int h = o >> 7, c = o & 127;
        #pragma unroll
        for (int t = 0; t < 16; ++t)
            acc += Wc[c * 384 + 256 + h * 16 + t] * Wsp[(h * 16 + t) * 128 + d];
        VP2t[idx] = f2b(acc);
    }
}

// ---------------------------------------------------------------------------
// bf16 MFMA GEMM, C[M,N] = A[M,K] @ Bt^T. Used only for qS now.
// ---------------------------------------------------------------------------
template<bool AF32, bool CF32>
__global__ __launch_bounds__(256) void gemm_bt(
    const void* __restrict__ Ap, const short* __restrict__ Bt,
    void* __restrict__ Cp, int M, int N, int K)
{
    __shared__ short As[128][72];
    __shared__ short Bs[128][72];
    const int tid  = threadIdx.x;
    const int bm   = blockIdx.y << 7, bn = blockIdx.x << 7;
    const int wave = tid >> 6, lane = tid & 63;
    const int wm   = (wave >> 1) << 6, wn = (wave & 1) << 6;
    const int row16 = lane & 15, kq = (lane >> 4) << 3;
    f32x4 acc[4][4] = {};

    for (int k0 = 0; k0 < K; k0 += 64) {
        if (AF32) {
            const float* A = (const float*)Ap;
            #pragma unroll
            for (int i = 0; i < 8; ++i) {
                int f = (i << 8) + tid;
                int r = f >> 4, c = (f & 15) << 2;
                f32x4 v = *(const f32x4*)(A + (size_t)(bm + r) * K + k0 + c);
                short4v t;
                t.x = f2b(v.x); t.y = f2b(v.y); t.z = f2b(v.z); t.w = f2b(v.w);
                *(short4v*)&As[r][c] = t;
            }
        } else {
            const short* A = (const short*)Ap;
            #pragma unroll
            for (int i = 0; i < 4; ++i) {
                int g = (i << 8) + tid;
                int r = g >> 3, c = (g & 7) << 3;
                *(bf16x8v*)&As[r][c] = *(const bf16x8v*)(A + (size_t)(bm + r) * K + k0 + c);
            }
        }
        #pragma unroll
        for (int i = 0; i < 4; ++i) {
            int g = (i << 8) + tid;
            int r = g >> 3, c = (g & 7) << 3;
            *(bf16x8v*)&Bs[r][c] = *(const bf16x8v*)(Bt + (size_t)(bn + r) * K + k0 + c);
        }
        __syncthreads();
        #pragma unroll
        for (int kk = 0; kk < 64; kk += 32) {
            bf16x8v afr[4], bfr[4];
            #pragma unroll
            for (int mi = 0; mi < 4; ++mi)
                afr[mi] = *(const bf16x8v*)&As[wm + (mi << 4) + row16][kq + kk];
            #pragma unroll
            for (int ni = 0; ni < 4; ++ni)
                bfr[ni] = *(const bf16x8v*)&Bs[wn + (ni << 4) + row16][kq + kk];
            #pragma unroll
            for (int mi = 0; mi < 4; ++mi)
                #pragma unroll
                for (int ni = 0; ni < 4; ++ni)
                    acc[mi][ni] = __builtin_amdgcn_mfma_f32_16x16x32_bf16(
                        afr[mi], bfr[ni], acc[mi][ni], 0, 0, 0);
        }
        __syncthreads();
    }

    const int col = lane & 15, rb = (lane >> 4) << 2;
    #pragma unroll
    for (int mi = 0; mi < 4; ++mi)
        #pragma unroll
        for (int ni = 0; ni < 4; ++ni)
            #pragma unroll
            for (int r = 0; r < 4; ++r) {
                int rr = bm + wm + (mi << 4) + rb + r;
                int cc = bn + wn + (ni << 4) + col;
                float v = acc[mi][ni][r];
                if (CF32) ((float*)Cp)[(size_t)rr * N + cc] = v;
                else      ((short*)Cp)[(size_t)rr * N + cc] = f2b(v);
            }
}

// ---------------------------------------------------------------------------
// Cross attention (XCD-swizzled: 10 queries of each b on the same XCD so the
// b's m-token slice is L2-shared -> m HBM ~472->~310 MB).
// ---------------------------------------------------------------------------
__global__ __launch_bounds__(256) void attn_cross(
    const float* __restrict__ m_token, const short* __restrict__ qS,
    const float* __restrict__ pe, const int* __restrict__ rel,
    short* __restrict__ u)
{
    __shared__ float mrows[32][132];
    __shared__ float qsr[1024];
    __shared__ int   selk[32];
    __shared__ float wts[8][32];
    // bijective swizzle: 28800 = 8 xcd * 360 b * 10 q
    const int phys = blockIdx.x;
    const int xcd  = phys & 7;
    const int slot = phys >> 3;
    const int b    = xcd * 360 + slot / A_N;
    const int q    = slot % A_N;
    const int bq   = b * A_N + q;
    const int tid = threadIdx.x;

    const int* relrow = rel + (size_t)bq * M_N;
    for (int k = tid; k < M_N; k += 256) {
        int r = relrow[k];
        if (r >= 0) selk[r] = k;
    }
    {
        short4v v = ((const short4v*)(qS + (size_t)bq * 1024))[tid];
        qsr[(tid << 2) + 0] = b2f(v.x);
        qsr[(tid << 2) + 1] = b2f(v.y);
        qsr[(tid << 2) + 2] = b2f(v.z);
        qsr[(tid << 2) + 3] = b2f(v.w);
    }
    __syncthreads();
    #pragma unroll
    for (int i = 0; i < 4; ++i) {
        int f = (i << 8) + tid;
        int r = f >> 5, c = (f & 31) << 2;
        f32x4 v = *(const f32x4*)(m_token + ((size_t)b * M_N + selk[r]) * DIMC + c);
        *(f32x4*)&mrows[r][c] = v;
    }
    __syncthreads();
    {
        const int h = tid >> 5, r = tid & 31;
        const float* qh = qsr + (h << 7);
        f32x4 p = {0.f, 0.f, 0.f, 0.f};
        #pragma unroll
        for (int d = 0; d < DIMC; d += 4)
            p += *(const f32x4*)(qh + d) * *(const f32x4*)&mrows[r][d];
        float sc = p.x + p.y + p.z + p.w + pe[((size_t)bq * 32 + r) * 8 + h];
        float mx = sc;
        #pragma unroll
        for (int off = 16; off; off >>= 1) mx = fmaxf(mx, __shfl_xor(mx, off, 32));
        float e = expf(sc - mx);
        float s = e;
        #pragma unroll
        for (int off = 16; off; off >>= 1) s += __shfl_xor(s, off, 32);
        wts[h][r] = e / s;
    }
    __syncthreads();
    {
        const int h = tid >> 5, d0 = (tid << 2) & 127;
        f32x4 acc = {0.f, 0.f, 0.f, 0.f};
        #pragma unroll
        for (int r = 0; r < 32; ++r)
            acc += wts[h][r] * *(const f32x4*)&mrows[r][d0];
        short4v t;
        t.x = f2b(acc.x); t.y = f2b(acc.y); t.z = f2b(acc.z); t.w = f2b(acc.w);
        *(short4v*)(u + (size_t)bq * 1024 + (tid << 2)) = t;
    }
}

// ---------------------------------------------------------------------------
// Fused back half, 4 batches per block (grid 720):
//  P0: y = u @ VP1          (M=40 pad48, N=128, K=1024, 8 K-chunks)
//  P2: yS2 = y @ S2         (per-head N-chunks) -> s2L[(bb,q,h)][d]
//  P3: scores = yS2 . y^T   (wave bb), softmax w/ rel mask + pe bias -> wLb
//  P4: Z = y @ VP2          (per-head) -> zL[(bb,k)][(h,d)]
//  P5: out[q,d] = sum_h sum_{3 sel k} w * Z[k][(h,d)]   (renormalized bf16 w)
// ---------------------------------------------------------------------------
__global__ __launch_bounds__(256, 1) void self_fused(
    const short* __restrict__ u_in, const short* __restrict__ VP1t,
    const short* __restrict__ S2t,  const short* __restrict__ VP2t,
    const float* __restrict__ pe,   const int* __restrict__ rel,
    float* __restrict__ outp)
{
    __shared__ short yL[48][136];     // 13056 B  y rows (40 valid + pad)
    __shared__ short bigS[43520];     // 87040 B  s2L[320][136] then zL[40][1040]
    __shared__ short bsL[128][136];   // 34816 B  streamed B panel
    __shared__ char  ureg[13056];     // P0: aL[48][136]; later: wLb[320][16]+relL[400]
    __shared__ float peL[960];        //  3840 B
    __shared__ int   selS[120];       //   480 B   (total 152288 B)

    short (*aL)[136]  = (short(*)[136])ureg;
    short (*wLb)[16]  = (short(*)[16])ureg;
    int*   relL       = (int*)(ureg + 10240);

    const int tid  = threadIdx.x;
    const int wave = tid >> 6, lane = tid & 63;
    const int row16 = lane & 15, kq = (lane >> 4) << 3;
    const int rb4   = (lane >> 4) << 2;
    const int b0    = blockIdx.x << 2;
    const size_t rowbase = (size_t)b0 * A_N;

    // ---- P0: y = u @ VP1 ----
    f32x4 cy[3][2] = {};
    for (int kc = 0; kc < 8; ++kc) {
        const int koff = kc << 7;
        for (int g = tid; g < 640; g += 256) {
            int r = g >> 4, c8 = (g & 15) << 3;
            *(bf16x8v*)&aL[r][c8] =
                *(const bf16x8v*)(u_in + (rowbase + r) * 1024 + koff + c8);
        }
        for (int g = tid; g < 2048; g += 256) {
            int r = g >> 4, c8 = (g & 15) << 3;
            *(bf16x8v*)&bsL[r][c8] =
                *(const bf16x8v*)(VP1t + (size_t)r * 1024 + koff + c8);
        }
        __syncthreads();
        #pragma unroll
        for (int j = 0; j < 2; ++j) {
            const int nt = (wave << 1) + j;
            bf16x8v bfr[4];
            #pragma unroll
            for (int ks = 0; ks < 4; ++ks)
                bfr[ks] = *(const bf16x8v*)&bsL[(nt << 4) + row16][(ks << 5) + kq];
            #pragma unroll
            for (int mt = 0; mt < 3; ++mt)
                #pragma unroll
                for (int ks = 0; ks < 4; ++ks) {
                    bf16x8v av = *(const bf16x8v*)&aL[(mt << 4) + row16][(ks << 5) + kq];
                    cy[mt][j] = __builtin_amdgcn_mfma_f32_16x16x32_bf16(
                        av, bfr[ks], cy[mt][j], 0, 0, 0);
                }
        }
        __syncthreads();
    }
    #pragma unroll
    for (int mt = 0; mt < 3; ++mt)
        #pragma unroll
        for (int j = 0; j < 2; ++j)
            #pragma unroll
            for (int r = 0; r < 4; ++r) {
                int a = (mt << 4) + rb4 + r;
                if (a < 40) yL[a][((wave << 1) + j) * 16 + row16] = f2b(cy[mt][j][r]);
            }
    for (int g = tid; g < 1088; g += 256) ((short*)yL)[5440 + g] = 0;  // pad rows
    __syncthreads();

    // persistent A-fragments of y (reused by P2 and P4)
    bf16x8v af[3][4];
    #pragma unroll
    for (int mt = 0; mt < 3; ++mt)
        #pragma unroll
        for (int ks = 0; ks < 4; ++ks)
            af[mt][ks] = *(const bf16x8v*)&yL[(mt << 4) + row16][(ks << 5) + kq];

    // rel / pe / selS into reused LDS (visibility via first P2 barrier)
    for (int g = tid; g < 400; g += 256) {
        int v = rel[(size_t)b0 * 100 + g];
        relL[g] = v;
        if (v >= 0) {
            int bb = g / 100, rem = g - bb * 100;
            int q = rem / 10, k = rem - q * 10;
            selS[bb * 30 + q * 3 + v] = k;
        }
    }
    for (int g = tid; g < 960; g += 256) peL[g] = pe[(size_t)b0 * 240 + g];

    // ---- P2: yS2 = y @ S2 -> s2L ----
    for (int h = 0; h < 8; ++h) {
        const int n0 = h << 7;
        for (int g = tid; g < 2048; g += 256) {
            int r = g >> 4, c8 = (g & 15) << 3;
            *(bf16x8v*)&bsL[r][c8] =
                *(const bf16x8v*)(S2t + (size_t)(n0 + r) * 128 + c8);
        }
        __syncthreads();
        f32x4 cc[3][2] = {};
        #pragma unroll
        for (int j = 0; j < 2; ++j) {
            const int nt = (wave << 1) + j;
            bf16x8v bfr[4];
            #pragma unroll
            for (int ks = 0; ks < 4; ++ks)
                bfr[ks] = *(const bf16x8v*)&bsL[(nt << 4) + row16][(ks << 5) + kq];
            #pragma unroll
            for (int mt = 0; mt < 3; ++mt)
                #pragma unroll
                for (int ks = 0; ks < 4; ++ks)
                    cc[mt][j] = __builtin_amdgcn_mfma_f32_16x16x32_bf16(
                        af[mt][ks], bfr[ks], cc[mt][j], 0, 0, 0);
        }
        #pragma unroll
        for (int mt = 0; mt < 3; ++mt)
            #pragma unroll
            for (int j = 0; j < 2; ++j)
                #pragma unroll
                for (int r = 0; r < 4; ++r) {
                    int a = (mt << 4) + rb4 + r;
                    if (a < 40) {
                        int bb = (a * 205) >> 11, q = a - bb * 10;
                        int d = ((wave << 1) + j) * 16 + row16;
                        bigS[(bb * 80 + q * 8 + h) * 136 + d] = f2b(cc[mt][j][r]);
                    }
                }
        __syncthreads();
    }

    // ---- P3: scores + softmax (wave = bb) ----
    {
        const int bb = wave;
        bf16x8v bfy[4];
        #pragma unroll
        for (int ks = 0; ks < 4; ++ks)
            bfy[ks] = *(const bf16x8v*)&yL[bb * 10 + row16][(ks << 5) + kq];
        f32x4 sa[5] = {};
        #pragma unroll
        for (int mt = 0; mt < 5; ++mt)
            #pragma unroll
            for (int ks = 0; ks < 4; ++ks) {
                bf16x8v av = *(const bf16x8v*)
                    &bigS[(bb * 80 + (mt << 4) + row16) * 136 + (ks << 5) + kq];
                sa[mt] = __builtin_amdgcn_mfma_f32_16x16x32_bf16(
                    av, bfy[ks], sa[mt], 0, 0, 0);
            }
        const int k = row16;
        #pragma unroll
        for (int mt = 0; mt < 5; ++mt)
            #pragma unroll
            for (int r = 0; r < 4; ++r) {
                int rowS = (mt << 4) + rb4 + r;
                int q = rowS >> 3, hh = rowS & 7;
                int rv = (k < 10) ? relL[bb * 100 + q * 10 + k] : -1;
                float bias = (rv >= 0) ? peL[bb * 240 + q * 24 + rv * 8 + hh] : 0.f;
                float s = (rv >= 0) ? sa[mt][r] + bias : -1e30f;
                float mx = s;
                mx = fmaxf(mx, __shfl_xor(mx, 8, 16));
                mx = fmaxf(mx, __shfl_xor(mx, 4, 16));
                mx = fmaxf(mx, __shfl_xor(mx, 2, 16));
                mx = fmaxf(mx, __shfl_xor(mx, 1, 16));
                float e = (rv >= 0) ? __expf(s - mx) : 0.f;
                float su = e;
                su += __shfl_xor(su, 8, 16);
                su += __shfl_xor(su, 4, 16);
                su += __shfl_xor(su, 2, 16);
                su += __shfl_xor(su, 1, 16);
                wLb[bb * 80 + rowS][k] = f2b(e / su);
            }
    }
    __syncthreads();

    // ---- P4: Z = y @ VP2 -> zL (overwrites s2L) ----
    for (int h = 0; h < 8; ++h) {
        const int n0 = h << 7;
        for (int g = tid; g < 2048; g += 256) {
            int r = g >> 4, c8 = (g & 15) << 3;
            *(bf16x8v*)&bsL[r][c8] =
                *(const bf16x8v*)(VP2t + (size_t)r * 1024 + n0 + c8);
        }
        __syncthreads();
        f32x4 cc[3][2] = {};
        #pragma unroll
        for (int j = 0; j < 2; ++j) {
            const int nt = (wave << 1) + j;
            bf16x8v bfr[4];
            #pragma unroll
            for (int ks = 0; ks < 4; ++ks)
                bfr[ks] = *(const bf16x8v*)&bsL[(nt << 4) + row16][(ks << 5) + kq];
            #pragma unroll
            for (int mt = 0; mt < 3; ++mt)
                #pragma unroll
                for (int ks = 0; ks < 4; ++ks)
                    cc[mt][j] = __builtin_amdgcn_mfma_f32_16x16x32_bf16(
                        af[mt][ks], bfr[ks], cc[mt][j], 0, 0, 0);
        }
        #pragma unroll
        for (int mt = 0; mt < 3; ++mt)
            #pragma unroll
            for (int j = 0; j < 2; ++j)
                #pragma unroll
                for (int r = 0; r < 4; ++r) {
                    int a = (mt << 4) + rb4 + r;
                    if (a < 40) {
                        int dl = ((wave << 1) + j) * 16 + row16;
                        bigS[a * 1040 + n0 + dl] = f2b(cc[mt][j][r]);
                    }
                }
        __syncthreads();
    }

    // ---- P5: combine (3 selected keys, renormalized weights) + store ----
    for (int idx = tid; idx < 1280; idx += 256) {
        int a = idx >> 5, d4 = (idx & 31) << 2;
        int bb = (a * 205) >> 11, q = a - bb * 10;
        f32x4 acc = {0.f, 0.f, 0.f, 0.f};
        #pragma unroll
        for (int hh = 0; hh < 8; ++hh) {
            int k0s = selS[bb * 30 + q * 3 + 0];
            int k1s = selS[bb * 30 + q * 3 + 1];
            int k2s = selS[bb * 30 + q * 3 + 2];
            float w0 = b2f(wLb[bb * 80 + q * 8 + hh][k0s]);
            float w1 = b2f(wLb[bb * 80 + q * 8 + hh][k1s]);
            float w2 = b2f(wLb[bb * 80 + q * 8 + hh][k2s]);
            float inv = 1.f / (w0 + w1 + w2);
            short4v z0 = *(const short4v*)&bigS[(bb * 10 + k0s) * 1040 + (hh << 7) + d4];
            short4v z1 = *(const short4v*)&bigS[(bb * 10 + k1s) * 1040 + (hh << 7) + d4];
            short4v z2 = *(const short4v*)&bigS[(bb * 10 + k2s) * 1040 + (hh << 7) + d4];
            w0 *= inv; w1 *= inv; w2 *= inv;
            acc.x += w0 * b2f(z0.x) + w1 * b2f(z1.x) + w2 * b2f(z2.x);
            acc.y += w0 * b2f(z0.y) + w1 * b2f(z1.y) + w2 * b2f(z2.y);
            acc.z += w0 * b2f(z0.z) + w1 * b2f(z1.z) + w2 * b2f(z2.z);
            acc.w += w0 * b2f(z0.w) + w1 * b2f(z1.w) + w2 * b2f(z2.w);
        }
        *(f32x4*)(outp + (rowbase + a) * 128 + d4) = acc;
    }
}

// ---------------------------------------------------------------------------
extern "C" void kernel_launch(void* const* d_in, const int* in_sizes, int n_in,
                              void* d_out, int out_size, void* d_ws, size_t ws_size,
                              hipStream_t stream)
{
    const float* a_token = (const float*)d_in[0];
    const float* m_token = (const float*)d_in[1];
    const float* a2m_pe  = (const float*)d_in[2];
    const float* a_pe    = (const float*)d_in[3];
    const float* Wq      = (const float*)d_in[4];
    const float* Wk      = (const float*)d_in[5];
    const float* Wv      = (const float*)d_in[6];
    const float* Wcp     = (const float*)d_in[7];
    const float* Wc      = (const float*)d_in[8];
    const float* Wsp     = (const float*)d_in[9];
    const int*   a2m_rel = (const int*)d_in[10];
    const int*   a_rel   = (const int*)d_in[11];

    char* ws = (char*)d_ws;
    short* S1t  = (short*)(ws + 0);
    short* VP1t = (short*)(ws + 262144);
    short* S2t  = (short*)(ws + 524288);
    short* VP2t = (short*)(ws + 786432);
    short* buf1 = (short*)(ws + 1048576);                  // qS   [28800][1024]
    short* buf2 = (short*)(ws + 1048576 + 58982400ull);    // u    [28800][1024]
    float* outp = (float*)d_out;

    precompute_mats<<<dim3(2048), dim3(256), 0, stream>>>(
        Wq, Wk, Wv, Wcp, Wc, Wsp, S1t, VP1t, S2t, VP2t);

    // qS = a_token @ S1   [28800,1024], K=128
    gemm_bt<true, false><<<dim3(8, 225), dim3(256), 0, stream>>>(
        (const void*)a_token, S1t, (void*)buf1, BQ_N, 1024, 128);

    attn_cross<<<dim3(BQ_N), dim3(256), 0, stream>>>(
        m_token, buf1, a2m_pe, a2m_rel, buf2);

    self_fused<<<dim3(720), dim3(256), 0, stream>>>(
        buf2, VP1t, S2t, VP2t, a_pe, a_rel, outp);
}